// Round 2
// baseline (472.314 us; speedup 1.0000x reference)
//
#include <hip/hip_runtime.h>
#include <hip/hip_bf16.h>

// GroupNLMSMemory: B=512, D=256, M=100000
// out = [retrieved 512x256 | attn 512x100000] (f32)
// No-max softmax (logits in [-10,10] -> exp safe). Two pipelines:
//  Path A (ws >= 135MB): k0,k0c(Kbf16+rkn),k0b(VT) -> k1b(sum) -> k2 -> k3<NORM> -> k4
//  Path B (ws >= 84MB, guaranteed): k0,k0c(rkn),k0b -> k3(unnorm+sums) -> k2 -> k5(rescale),k4

#define MCOLS 100000
#define MP    100032              // VT padded cols (mult of 64, zero-filled tail)
#define DDIM  256
#define CHUNK 1664                // 26 tiles of 64 -> grid 61x4 = 244 blocks (~1/CU)
#define NTFULL 26
#define NCHUNK 61
#define NST2  122                 // NCHUNK*2 partial-sum entries
#define ATTN_OFF 131072
#define WS_RXN  0
#define WS_RKN  512
#define WS_RCPL 100512
#define WS_VT_BYTE   1048576ull
#define WS_VT_END    (WS_VT_BYTE + 2ull*DDIM*MP)            // 52,264,960
#define WS_PART_BYTE 52264960ull
#define WS_PART_END  (WS_PART_BYTE + 4ull*NCHUNK*512*256)   // 84,246,528
#define WS_KB_BYTE   84246528ull
#define WS_KB_END    (WS_KB_BYTE + 2ull*(size_t)MCOLS*DDIM) // 135,446,528

typedef short short8 __attribute__((ext_vector_type(8)));
typedef float f32x4  __attribute__((ext_vector_type(4)));

static __device__ __forceinline__ unsigned short f2bfu(float f) {
  union { __hip_bfloat16 h; unsigned short u; } cv;
  cv.h = __float2bfloat16(f);
  return cv.u;
}
static __device__ __forceinline__ unsigned int pk2(float a, float b) {
  return (unsigned int)f2bfu(a) | ((unsigned int)f2bfu(b) << 16);
}
static __device__ __forceinline__ short8 pack8(float4 a, float4 b) {
  short8 r;
  r[0] = (short)f2bfu(a.x); r[1] = (short)f2bfu(a.y);
  r[2] = (short)f2bfu(a.z); r[3] = (short)f2bfu(a.w);
  r[4] = (short)f2bfu(b.x); r[5] = (short)f2bfu(b.y);
  r[6] = (short)f2bfu(b.z); r[7] = (short)f2bfu(b.w);
  return r;
}

// ---------------- k0: x row norms (folds TEMP=10) ----------------
__global__ void k0_xn(const float* __restrict__ x, float* __restrict__ ws) {
  const int b = blockIdx.x, t = threadIdx.x;
  const float v = x[b*DDIM + t];
  float s = v*v;
  #pragma unroll
  for (int mk = 1; mk <= 32; mk <<= 1) s += __shfl_xor(s, mk);
  __shared__ float ps[4];
  if ((t & 63) == 0) ps[t >> 6] = s;
  __syncthreads();
  if (t == 0) {
    const float tot = ps[0] + ps[1] + ps[2] + ps[3];
    ws[WS_RXN + b] = 10.0f / fmaxf(sqrtf(tot), 1e-12f);
  }
}

// ---------------- k0c: K row norms (+ optional Kbf16) ----------------
template<bool WRITEKB>
__global__ __launch_bounds__(256) void k0c_kn(const float* __restrict__ K,
                                              float* __restrict__ ws) {
  const int t = threadIdx.x;
  const int mg = blockIdx.x*64 + (t >> 2);
  const int qq = t & 3;
  if (mg >= MCOLS) return;
  const float* kp = K + (size_t)mg*DDIM + 64*qq;
  unsigned int* kb = (unsigned int*)((char*)ws + WS_KB_BYTE);
  float ss = 0.f;
  #pragma unroll
  for (int j = 0; j < 8; ++j) {
    const float4 a = *(const float4*)(kp + 8*j);
    const float4 b = *(const float4*)(kp + 8*j + 4);
    ss += a.x*a.x + a.y*a.y + a.z*a.z + a.w*a.w
        + b.x*b.x + b.y*b.y + b.z*b.z + b.w*b.w;
    if (WRITEKB) {
      uint4 u;
      u.x = pk2(a.x, a.y); u.y = pk2(a.z, a.w);
      u.z = pk2(b.x, b.y); u.w = pk2(b.z, b.w);
      *(uint4*)(kb + (size_t)mg*128 + 32*qq + 4*j) = u;
    }
  }
  ss += __shfl_xor(ss, 1); ss += __shfl_xor(ss, 2);
  if (qq == 0) ws[WS_RKN + mg] = 1.0f / fmaxf(sqrtf(ss), 1e-12f);
}

// ---------------- k0b: transpose V -> VT bf16 [256][MP] ----------------
__global__ __launch_bounds__(256) void k0b_tr(const float* __restrict__ V,
                                              float* __restrict__ ws) {
  const int t = threadIdx.x;
  const int m0 = blockIdx.x * 64;
  __shared__ float vt_f[64][261];
  #pragma unroll
  for (int i = 0; i < 4; ++i) {
    const int ml = (t >> 4) + 16*i;
    const int mg = m0 + ml;
    #pragma unroll
    for (int j = 0; j < 4; ++j) {
      const int d = 4*(t & 15) + 64*j;
      float4 v = make_float4(0.f, 0.f, 0.f, 0.f);
      if (mg < MCOLS) v = *(const float4*)(V + (size_t)mg*DDIM + d);
      vt_f[ml][d] = v.x; vt_f[ml][d+1] = v.y; vt_f[ml][d+2] = v.z; vt_f[ml][d+3] = v.w;
    }
  }
  __syncthreads();
  unsigned short* vt = (unsigned short*)((char*)ws + WS_VT_BYTE);
  const int mq = 4*(t & 15);
  #pragma unroll
  for (int it = 0; it < 16; ++it) {
    const int d = (t >> 4) + 16*it;
    uint2 u;
    u.x = pk2(vt_f[mq+0][d], vt_f[mq+1][d]);
    u.y = pk2(vt_f[mq+2][d], vt_f[mq+3][d]);
    *(uint2*)(vt + (size_t)d*MP + m0 + mq) = u;
  }
}

// ---------------- x fragment loader (verified round-1) ----------------
static __device__ __forceinline__ void load_xf(const float* __restrict__ x,
                                               int brow0, int q, int ln,
                                               short8 xf[2][8]) {
  #pragma unroll
  for (int as = 0; as < 2; ++as) {
    const int row = brow0 + 16*as + ln;
    #pragma unroll
    for (int kk = 0; kk < 8; ++kk) {
      const float* p = x + row*DDIM + 32*kk + 8*q;
      const float4 v0 = *(const float4*)p;
      const float4 v1 = *(const float4*)(p + 4);
      xf[as][kk] = pack8(v0, v1);
    }
  }
}

// ---------------- k1b (path A): sum-of-exp, no LDS, no barriers ----------------
__global__ __launch_bounds__(512, 4) void k1b_sum(const float* __restrict__ x,
                                                  const float* __restrict__ ws,
                                                  float* __restrict__ out) {
  const int c = blockIdx.x, rb = blockIdx.y;
  const int t = threadIdx.x, w = t >> 6, l = t & 63, q = l >> 4, ln = l & 15;
  const int h = w & 1;
  short8 xf[2][8];
  const int brow0 = rb*128 + 32*(w >> 1);
  load_xf(x, brow0, q, ln, xf);
  float rxn[2][4];
  #pragma unroll
  for (int as = 0; as < 2; ++as)
    #pragma unroll
    for (int r = 0; r < 4; ++r)
      rxn[as][r] = ws[WS_RXN + brow0 + 16*as + 4*q + r];
  const unsigned short* kb = (const unsigned short*)((const char*)ws + WS_KB_BYTE);
  const float* rknw = ws + WS_RKN;
  float lpr[2][4] = {{0.f,0.f,0.f,0.f},{0.f,0.f,0.f,0.f}};
  const int mbase = c*CHUNK;
  const int nt = min(NTFULL, (MCOLS - mbase + 63) >> 6);
  for (int mt = 0; mt < nt; ++mt) {
    const int m0 = mbase + mt*64;
    const int mr0 = m0 + 32*h + ln, mr1 = mr0 + 16;
    const int kr0 = min(mr0, MCOLS-1), kr1 = min(mr1, MCOLS-1);
    const unsigned short* p0 = kb + (size_t)kr0*DDIM + 8*q;
    const unsigned short* p1 = kb + (size_t)kr1*DDIM + 8*q;
    f32x4 acc[2][2];
    #pragma unroll
    for (int as = 0; as < 2; ++as)
      #pragma unroll
      for (int mm = 0; mm < 2; ++mm) { f32x4 z = {0.f,0.f,0.f,0.f}; acc[as][mm] = z; }
    #pragma unroll
    for (int kk = 0; kk < 8; ++kk) {
      const short8 b0 = *(const short8*)(p0 + 32*kk);
      const short8 b1 = *(const short8*)(p1 + 32*kk);
      acc[0][0] = __builtin_amdgcn_mfma_f32_16x16x32_bf16(xf[0][kk], b0, acc[0][0], 0,0,0);
      acc[0][1] = __builtin_amdgcn_mfma_f32_16x16x32_bf16(xf[0][kk], b1, acc[0][1], 0,0,0);
      acc[1][0] = __builtin_amdgcn_mfma_f32_16x16x32_bf16(xf[1][kk], b0, acc[1][0], 0,0,0);
      acc[1][1] = __builtin_amdgcn_mfma_f32_16x16x32_bf16(xf[1][kk], b1, acc[1][1], 0,0,0);
    }
    const float rk0 = rknw[kr0], rk1 = rknw[kr1];
    const bool ok0 = mr0 < MCOLS, ok1 = mr1 < MCOLS;
    #pragma unroll
    for (int as = 0; as < 2; ++as)
      #pragma unroll
      for (int r = 0; r < 4; ++r)
        lpr[as][r] += (ok0 ? __expf(acc[as][0][r]*rxn[as][r]*rk0) : 0.f)
                    + (ok1 ? __expf(acc[as][1][r]*rxn[as][r]*rk1) : 0.f);
  }
  #pragma unroll
  for (int as = 0; as < 2; ++as)
    #pragma unroll
    for (int r = 0; r < 4; ++r) {
      float s = lpr[as][r];
      s += __shfl_xor(s, 1); s += __shfl_xor(s, 2);
      s += __shfl_xor(s, 4); s += __shfl_xor(s, 8);
      if (ln == 0)
        out[(size_t)(c*2 + h)*512 + rb*128 + 32*(w >> 1) + 16*as + 4*q + r] = s;
    }
}

// ---------------- k2: merge chunk sums -> 1/l ----------------
__global__ void k2_final(const float* __restrict__ out, float* __restrict__ ws) {
  const int b = blockIdx.x, t = threadIdx.x;   // 512 x 128
  float v = (t < NST2) ? out[(size_t)t*512 + b] : 0.f;
  #pragma unroll
  for (int mk = 1; mk <= 32; mk <<= 1) v += __shfl_xor(v, mk);
  __shared__ float s2[2];
  if ((t & 63) == 0) s2[t >> 6] = v;
  __syncthreads();
  if (t == 0) ws[WS_RCPL + b] = 1.0f / (s2[0] + s2[1]);
}

// ---------------- k3: main fused kernel ----------------
template<bool USEKB, bool NORM>
__global__ __launch_bounds__(512, 2) void k3_main(const float* __restrict__ x,
                                                  const float* __restrict__ K,
                                                  float* __restrict__ ws,
                                                  float* __restrict__ out) {
  const int c = blockIdx.x, rb = blockIdx.y;
  const int t = threadIdx.x, w = t >> 6, l = t & 63, q = l >> 4, ln = l & 15;
  const int h = w & 1;
  __shared__ __align__(16) unsigned short plds[2][128][72];  // double-buffered p tile
  short8 xf[2][8];
  const int brow0 = rb*128 + 32*(w >> 1);
  load_xf(x, brow0, q, ln, xf);
  float rxn[2][4], rlq[2][4];
  #pragma unroll
  for (int as = 0; as < 2; ++as)
    #pragma unroll
    for (int r = 0; r < 4; ++r) {
      const int row = brow0 + 16*as + 4*q + r;
      rxn[as][r] = ws[WS_RXN + row];
      rlq[as][r] = NORM ? ws[WS_RCPL + row] : 0.f;
    }
  float lpr[2][4] = {{0.f,0.f,0.f,0.f},{0.f,0.f,0.f,0.f}};
  f32x4 apv[2][8];
  #pragma unroll
  for (int bs = 0; bs < 2; ++bs)
    #pragma unroll
    for (int dx = 0; dx < 8; ++dx) { f32x4 z = {0.f,0.f,0.f,0.f}; apv[bs][dx] = z; }
  const int b2 = 32*(w & 3), d2 = 128*(w >> 2);
  const unsigned short* vt = (const unsigned short*)((const char*)ws + WS_VT_BYTE);
  const unsigned short* kb = (const unsigned short*)((const char*)ws + WS_KB_BYTE);
  const float* rknw = ws + WS_RKN;
  float* attn = out + ATTN_OFF;
  const int mbase = c*CHUNK;
  const int nt = min(NTFULL, (MCOLS - mbase + 63) >> 6);

  for (int mt = 0; mt < nt; ++mt) {
    const int m0 = mbase + mt*64;
    // prefetch PV ks=0 B-frags (land during QK^T)
    short8 bvp[8];
    #pragma unroll
    for (int dx = 0; dx < 8; ++dx)
      bvp[dx] = *(const short8*)(vt + (size_t)(d2 + 16*dx + ln)*MP + m0 + 8*q);
    // QK^T: direct global fragment loads
    const int mr0 = m0 + 32*h + ln, mr1 = mr0 + 16;
    const int kr0 = min(mr0, MCOLS-1), kr1 = min(mr1, MCOLS-1);
    f32x4 acc[2][2];
    #pragma unroll
    for (int as = 0; as < 2; ++as)
      #pragma unroll
      for (int mm = 0; mm < 2; ++mm) { f32x4 z = {0.f,0.f,0.f,0.f}; acc[as][mm] = z; }
    if (USEKB) {
      const unsigned short* p0 = kb + (size_t)kr0*DDIM + 8*q;
      const unsigned short* p1 = kb + (size_t)kr1*DDIM + 8*q;
      #pragma unroll
      for (int kk = 0; kk < 8; ++kk) {
        const short8 b0 = *(const short8*)(p0 + 32*kk);
        const short8 b1 = *(const short8*)(p1 + 32*kk);
        acc[0][0] = __builtin_amdgcn_mfma_f32_16x16x32_bf16(xf[0][kk], b0, acc[0][0], 0,0,0);
        acc[0][1] = __builtin_amdgcn_mfma_f32_16x16x32_bf16(xf[0][kk], b1, acc[0][1], 0,0,0);
        acc[1][0] = __builtin_amdgcn_mfma_f32_16x16x32_bf16(xf[1][kk], b0, acc[1][0], 0,0,0);
        acc[1][1] = __builtin_amdgcn_mfma_f32_16x16x32_bf16(xf[1][kk], b1, acc[1][1], 0,0,0);
      }
    } else {
      const float* p0 = K + (size_t)kr0*DDIM + 8*q;
      const float* p1 = K + (size_t)kr1*DDIM + 8*q;
      #pragma unroll
      for (int kk = 0; kk < 8; ++kk) {
        const short8 b0 = pack8(*(const float4*)(p0 + 32*kk), *(const float4*)(p0 + 32*kk + 4));
        const short8 b1 = pack8(*(const float4*)(p1 + 32*kk), *(const float4*)(p1 + 32*kk + 4));
        acc[0][0] = __builtin_amdgcn_mfma_f32_16x16x32_bf16(xf[0][kk], b0, acc[0][0], 0,0,0);
        acc[0][1] = __builtin_amdgcn_mfma_f32_16x16x32_bf16(xf[0][kk], b1, acc[0][1], 0,0,0);
        acc[1][0] = __builtin_amdgcn_mfma_f32_16x16x32_bf16(xf[1][kk], b0, acc[1][0], 0,0,0);
        acc[1][1] = __builtin_amdgcn_mfma_f32_16x16x32_bf16(xf[1][kk], b1, acc[1][1], 0,0,0);
      }
    }
    const float rk0 = rknw[kr0], rk1 = rknw[kr1];
    const bool ok0 = mr0 < MCOLS, ok1 = mr1 < MCOLS;
    #pragma unroll
    for (int as = 0; as < 2; ++as)
      #pragma unroll
      for (int r = 0; r < 4; ++r) {
        const int rowl = 32*(w >> 1) + 16*as + 4*q + r;
        const float p0v = ok0 ? __expf(acc[as][0][r]*rxn[as][r]*rk0) : 0.f;
        const float p1v = ok1 ? __expf(acc[as][1][r]*rxn[as][r]*rk1) : 0.f;
        float* arow = attn + (size_t)(rb*128 + rowl)*MCOLS;
        if (NORM) {
          if (ok0) arow[mr0] = p0v*rlq[as][r];
          if (ok1) arow[mr1] = p1v*rlq[as][r];
        } else {
          if (ok0) arow[mr0] = p0v;
          if (ok1) arow[mr1] = p1v;
          lpr[as][r] += p0v + p1v;
        }
        plds[mt & 1][rowl][32*h + ln]      = f2bfu(p0v);
        plds[mt & 1][rowl][32*h + 16 + ln] = f2bfu(p1v);
      }
    __syncthreads();   // single barrier/tile: plds[mt&1] ready; safe vs mt+2 rewrite
    // PV: A from plds, B from VT global (ks0 prefetched)
    short8 af0[2], af1[2];
    #pragma unroll
    for (int ks = 0; ks < 2; ++ks) {
      af0[ks] = *(const short8*)&plds[mt & 1][b2 + ln][32*ks + 8*q];
      af1[ks] = *(const short8*)&plds[mt & 1][b2 + 16 + ln][32*ks + 8*q];
    }
    #pragma unroll
    for (int dx = 0; dx < 8; ++dx) {
      apv[0][dx] = __builtin_amdgcn_mfma_f32_16x16x32_bf16(af0[0], bvp[dx], apv[0][dx], 0,0,0);
      apv[1][dx] = __builtin_amdgcn_mfma_f32_16x16x32_bf16(af1[0], bvp[dx], apv[1][dx], 0,0,0);
    }
    #pragma unroll
    for (int dx = 0; dx < 8; ++dx) {
      const short8 bv = *(const short8*)(vt + (size_t)(d2 + 16*dx + ln)*MP + m0 + 32 + 8*q);
      apv[0][dx] = __builtin_amdgcn_mfma_f32_16x16x32_bf16(af0[1], bv, apv[0][dx], 0,0,0);
      apv[1][dx] = __builtin_amdgcn_mfma_f32_16x16x32_bf16(af1[1], bv, apv[1][dx], 0,0,0);
    }
  }

  if (!NORM) {
    #pragma unroll
    for (int as = 0; as < 2; ++as)
      #pragma unroll
      for (int r = 0; r < 4; ++r) {
        float s = lpr[as][r];
        s += __shfl_xor(s, 1); s += __shfl_xor(s, 2);
        s += __shfl_xor(s, 4); s += __shfl_xor(s, 8);
        if (ln == 0)
          out[(size_t)(c*2 + h)*512 + rb*128 + 32*(w >> 1) + 16*as + 4*q + r] = s;
      }
  }
  float* part = (float*)((char*)ws + WS_PART_BYTE);
  float rlp[2][4];
  #pragma unroll
  for (int bs = 0; bs < 2; ++bs)
    #pragma unroll
    for (int r = 0; r < 4; ++r)
      rlp[bs][r] = NORM ? ws[WS_RCPL + rb*128 + b2 + 16*bs + 4*q + r] : 1.f;
  #pragma unroll
  for (int bs = 0; bs < 2; ++bs)
    #pragma unroll
    for (int dx = 0; dx < 8; ++dx)
      #pragma unroll
      for (int r = 0; r < 4; ++r) {
        const int row = rb*128 + b2 + 16*bs + 4*q + r;
        const int dcol = d2 + 16*dx + ln;
        part[((size_t)c*512 + row)*256 + dcol] = apv[bs][dx][r]*rlp[bs][r];
      }
}

// ---------------- k4: reduce retrieved partials ----------------
template<bool NORM>
__global__ void k4_red(const float* __restrict__ ws, float* __restrict__ out) {
  const int b = blockIdx.x, t = threadIdx.x;
  const float* part = (const float*)((const char*)ws + WS_PART_BYTE);
  float acc = 0.f;
  for (int cc = 0; cc < NCHUNK; ++cc)
    acc += part[((size_t)cc*512 + b)*256 + t];
  if (!NORM) acc *= ws[WS_RCPL + b];
  out[b*DDIM + t] = acc;
}

// ---------------- k5 (path B): rescale attn by 1/l ----------------
__global__ void k5_scale(const float* __restrict__ ws, float* __restrict__ out) {
  const int row = blockIdx.y;
  const int i4 = blockIdx.x*256 + threadIdx.x;
  if (i4 >= MCOLS/4) return;
  const float s = ws[WS_RCPL + row];
  float4* p = (float4*)(out + ATTN_OFF + (size_t)row*MCOLS) + i4;
  float4 v = *p;
  v.x *= s; v.y *= s; v.z *= s; v.w *= s;
  *p = v;
}

extern "C" void kernel_launch(void* const* d_in, const int* in_sizes, int n_in,
                              void* d_out, int out_size, void* d_ws, size_t ws_size,
                              hipStream_t stream) {
  const float* x = (const float*)d_in[0];
  const float* K = (const float*)d_in[1];
  const float* V = (const float*)d_in[2];
  float* out = (float*)d_out;
  float* ws  = (float*)d_ws;
  const bool useKB = ws_size >= WS_KB_END;   // round-1 proved ws >= 117.6MB >= PART_END

  k0_xn<<<512, 256, 0, stream>>>(x, ws);
  if (useKB) k0c_kn<true ><<<1563, 256, 0, stream>>>(K, ws);
  else       k0c_kn<false><<<1563, 256, 0, stream>>>(K, ws);
  k0b_tr<<<MP/64, 256, 0, stream>>>(V, ws);
  const dim3 g3(NCHUNK, 4);
  if (useKB) {                               // Path A: cheap sum pass, normalized write
    k1b_sum<<<g3, 512, 0, stream>>>(x, ws, out);
    k2_final<<<512, 128, 0, stream>>>(out, ws);
    k3_main<true, true><<<g3, 512, 0, stream>>>(x, K, ws, out);
    k4_red<true><<<512, 256, 0, stream>>>(ws, out);
  } else {                                   // Path B: one pass + rescale
    k3_main<false, false><<<g3, 512, 0, stream>>>(x, K, ws, out);
    k2_final<<<512, 128, 0, stream>>>(out, ws);
    k5_scale<<<dim3((MCOLS/4 + 255)/256, 512), 256, 0, stream>>>(ws, out);
    k4_red<false><<<512, 256, 0, stream>>>(ws, out);
  }
}